// Round 2
// baseline (5813.658 us; speedup 1.0000x reference)
//
#include <hip/hip_runtime.h>
#include <cmath>

typedef unsigned short u16;
typedef unsigned int   u32;
typedef short s16x8 __attribute__((ext_vector_type(8)));
typedef float f32x4 __attribute__((ext_vector_type(4)));

#define D_  1024
#define H_  16
#define NL_ 6
#define B_  16
#define L_  64
#define T_  192
#define NB_ 100
#define DF_ 4096
#define BT_ (B_*T_)   /* 3072 rows in stream */
#define BL_ (B_*L_)   /* 1024 rows per modality */

__device__ __forceinline__ float b2f(u16 u){ u32 x = ((u32)u)<<16; return __uint_as_float(x); }
__device__ __forceinline__ u16 f2b(float f){ u32 x = __float_as_uint(f); x += 0x7fffu + ((x>>16)&1u); return (u16)(x>>16); }
__device__ __forceinline__ float gelu_f(float v){ return 0.5f*v*(1.0f+erff(v*0.70710678118f)); }

// ---------------------------------------------------------------------------
// Small VALU GEMM for the K=91 / K=27 embedding first layers (trivial FLOPs).
// out = gelu(A(1024xK) @ W(Kx1024) + bias) -> bf16 internal buffer.
// ---------------------------------------------------------------------------
__global__ __launch_bounds__(256) void embed1_kernel(const float* __restrict__ A,
                                                     const float* __restrict__ W,
                                                     const float* __restrict__ bias,
                                                     u16* __restrict__ out, int K)
{
    int idx = blockIdx.x*256 + threadIdx.x;     // 1024*1024 outputs
    int m = idx >> 10, n = idx & 1023;
    float acc = bias[n];
    for (int k = 0; k < K; ++k)
        acc += A[m*K + k] * W[k*1024 + n];
    out[idx] = f2b(gelu_f(acc));
}

// ---------------------------------------------------------------------------
// rtg embedding:  s=leaky(rtg*w); s=s+s@R; softmax; eR = (p.bv)*w_d + (sum p)*b_d
// one 128-thread block per (b,l) row.
// ---------------------------------------------------------------------------
__global__ __launch_bounds__(128) void rtg_kernel(const float* __restrict__ rtgs,
                                                  const float* __restrict__ ret_w,
                                                  const float* __restrict__ res_w,
                                                  const float* __restrict__ bucket_w,
                                                  const float* __restrict__ bucket_b,
                                                  float* __restrict__ eR)
{
    int r = blockIdx.x, tid = threadIdx.x;
    __shared__ float sarr[NB_];
    __shared__ float red[128];
    float rtg = rtgs[r];
    float s = 0.f;
    if (tid < NB_) {
        float v = rtg * ret_w[tid];
        s = (v > 0.f) ? v : 0.01f*v;         // jax leaky_relu default slope
        sarr[tid] = s;
    }
    __syncthreads();
    float s2 = -1e30f;
    if (tid < NB_) {
        float acc = s;
        for (int m = 0; m < NB_; ++m) acc += sarr[m] * res_w[m*NB_ + tid];
        s2 = acc;
    }
    red[tid] = s2; __syncthreads();
    for (int off = 64; off > 0; off >>= 1) { if (tid < off) red[tid] = fmaxf(red[tid], red[tid+off]); __syncthreads(); }
    float mx = red[0]; __syncthreads();
    float e = (tid < NB_) ? expf(s2 - mx) : 0.f;
    red[tid] = e; __syncthreads();
    for (int off = 64; off > 0; off >>= 1) { if (tid < off) red[tid] += red[tid+off]; __syncthreads(); }
    float S = red[0]; __syncthreads();
    float bv = (100.f/99.f) * (float)tid;
    red[tid] = e * bv; __syncthreads();
    for (int off = 64; off > 0; off >>= 1) { if (tid < off) red[tid] += red[tid+off]; __syncthreads(); }
    float EB = red[0];
    float inv = 1.f/(1e-8f + S);
    float c = EB * inv, sg = S * inv;
    for (int d = tid; d < D_; d += 128)
        eR[(size_t)r*D_ + d] = c*bucket_w[d] + sg*bucket_b[d];
}

// ---------------------------------------------------------------------------
// assemble: x[b,3l+c,:] = emb_c[b,l,:] + pos[3l+c,:]   (f32 stream)
// ---------------------------------------------------------------------------
__global__ __launch_bounds__(256) void assemble_kernel(const float* __restrict__ eR,
                                                       const float* __restrict__ eS,
                                                       const float* __restrict__ eA,
                                                       const float* __restrict__ pos,
                                                       float* __restrict__ xf)
{
    int idx = blockIdx.x*256 + threadIdx.x;       // BT_*D_
    int row = idx >> 10, d = idx & 1023;
    int b = row / T_, t = row % T_;
    int l = t / 3, c = t % 3;
    const float* src = (c == 0) ? eR : (c == 1) ? eS : eA;
    xf[idx] = src[(size_t)(b*L_ + l)*D_ + d] + pos[(size_t)t*D_ + d];
}

// ---------------------------------------------------------------------------
// LayerNorm rows of f32 stream -> bf16 (GEMM A input)
// ---------------------------------------------------------------------------
__global__ __launch_bounds__(256) void ln_kernel(const float* __restrict__ x,
                                                 const float* __restrict__ g,
                                                 const float* __restrict__ bb,
                                                 u16* __restrict__ out)
{
    int row = blockIdx.x, tid = threadIdx.x;
    __shared__ float rs[256], rq[256];
    float4 v = ((const float4*)(x + (size_t)row*D_))[tid];
    rs[tid] = v.x+v.y+v.z+v.w;
    rq[tid] = v.x*v.x+v.y*v.y+v.z*v.z+v.w*v.w;
    __syncthreads();
    for (int off = 128; off > 0; off >>= 1) { if (tid < off){ rs[tid]+=rs[tid+off]; rq[tid]+=rq[tid+off]; } __syncthreads(); }
    float mean = rs[0]*(1.f/(float)D_);
    float var  = rq[0]*(1.f/(float)D_) - mean*mean;
    float rstd = rsqrtf(var + 1e-5f);
    int d0 = tid*4;
    ushort4 ov;
    ov.x = f2b((v.x-mean)*rstd*g[d0+0] + bb[d0+0]);
    ov.y = f2b((v.y-mean)*rstd*g[d0+1] + bb[d0+1]);
    ov.z = f2b((v.z-mean)*rstd*g[d0+2] + bb[d0+2]);
    ov.w = f2b((v.w-mean)*rstd*g[d0+3] + bb[d0+3]);
    ((ushort4*)(out + (size_t)row*D_))[tid] = ov;
}

// ---------------------------------------------------------------------------
// MFMA bf16 GEMM: C(MxN) = act(A(MxK) @ W(KxN) + bias) [+ res].
// A is bf16 (internal buffer), W is f32 (input weights) converted to bf16
// during LDS staging. 128x128 tile / 4 waves / BK=32, 16x16x32 bf16 MFMA.
// As row-major stride 40 (aligned b128 frag reads); Bs transposed [n][k]
// stride 42 elems (21 dwords, ≡1 mod 4 => staging writes spread over banks).
// ---------------------------------------------------------------------------
template<int GELU_ACT>
__global__ __launch_bounds__(256) void gemm128(const u16* __restrict__ A,
                                               const float* __restrict__ W,
                                               const float* __restrict__ bias,
                                               const float* res,
                                               float* outF,
                                               u16* outB,
                                               int M, int N, int K)
{
    __shared__ __align__(16) u16 As[128*40];
    __shared__ __align__(16) u16 Bs[128*42];
    int tid = threadIdx.x;
    int n0 = blockIdx.x * 128;
    int m0 = blockIdx.y * 128;
    int wave = tid >> 6, lane = tid & 63;
    int wm = (wave >> 1) * 64, wn = (wave & 1) * 64;
    int lr = lane & 15, lq = lane >> 4;

    f32x4 acc[4][4];
#pragma unroll
    for (int i = 0; i < 4; ++i)
#pragma unroll
        for (int j = 0; j < 4; ++j) acc[i][j] = (f32x4){0.f,0.f,0.f,0.f};

    int arow = tid >> 2, aq = tid & 3;   // A stage: rows 0..63 (+64), 4x8-elem chunks
    int kp = tid >> 4, cc = tid & 15;    // B stage: k-pair 0..15, col-chunk 0..15

    for (int k0 = 0; k0 < K; k0 += 32) {
        // stage A (bf16 row-major, vector copy)
        *(int4*)(As + arow*40 + aq*8)      = *(const int4*)(A + (size_t)(m0+arow)*K    + k0 + aq*8);
        *(int4*)(As + (64+arow)*40 + aq*8) = *(const int4*)(A + (size_t)(m0+64+arow)*K + k0 + aq*8);
        // stage B transposed + f32->bf16 cvt: Bs[n][k]
        {
            const float* wp = W + (size_t)(k0 + 2*kp)*N + n0 + cc*8;
            float4 r0a = *(const float4*)(wp);
            float4 r0b = *(const float4*)(wp + 4);
            float4 r1a = *(const float4*)(wp + N);
            float4 r1b = *(const float4*)(wp + N + 4);
            float r0[8] = {r0a.x,r0a.y,r0a.z,r0a.w, r0b.x,r0b.y,r0b.z,r0b.w};
            float r1[8] = {r1a.x,r1a.y,r1a.z,r1a.w, r1b.x,r1b.y,r1b.z,r1b.w};
#pragma unroll
            for (int i = 0; i < 8; ++i) {
                *(u32*)(Bs + (cc*8 + i)*42 + 2*kp) = (u32)f2b(r0[i]) | ((u32)f2b(r1[i]) << 16);
            }
        }
        __syncthreads();

        s16x8 af[4], bf[4];
#pragma unroll
        for (int i = 0; i < 4; ++i)
            af[i] = *(const s16x8*)(As + (wm + i*16 + lr)*40 + lq*8);
#pragma unroll
        for (int j = 0; j < 4; ++j) {
            const int* bp = (const int*)(Bs + (wn + j*16 + lr)*42 + lq*8);
            union { int i4[4]; s16x8 v; } u;
            u.i4[0]=bp[0]; u.i4[1]=bp[1]; u.i4[2]=bp[2]; u.i4[3]=bp[3];
            bf[j] = u.v;
        }
#pragma unroll
        for (int i = 0; i < 4; ++i)
#pragma unroll
            for (int j = 0; j < 4; ++j)
                acc[i][j] = __builtin_amdgcn_mfma_f32_16x16x32_bf16(af[i], bf[j], acc[i][j], 0, 0, 0);
        __syncthreads();
    }

    // epilogue: D row = quad*4+reg, col = lane&15
#pragma unroll
    for (int i = 0; i < 4; ++i) {
        int mbase = m0 + wm + i*16 + lq*4;
#pragma unroll
        for (int j = 0; j < 4; ++j) {
            int n = n0 + wn + j*16 + lr;
            float bvl = bias[n];
#pragma unroll
            for (int r = 0; r < 4; ++r) {
                int m = mbase + r;
                float v = acc[i][j][r] + bvl;
                if (GELU_ACT) v = gelu_f(v);
                size_t off = (size_t)m*N + n;
                if (res)  v += res[off];
                if (outF) outF[off] = v;
                if (outB) outB[off] = f2b(v);
            }
        }
    }
}

// ---------------------------------------------------------------------------
// Attention: wave per (b,h,t) query row. Two-pass softmax, causal.
// q,k,v,y stored bf16 [B*T][D] with col = h*64+d.
// ---------------------------------------------------------------------------
__global__ __launch_bounds__(256) void attn_kernel(const u16* __restrict__ qb,
                                                   const u16* __restrict__ kb,
                                                   const u16* __restrict__ vb,
                                                   u16* __restrict__ yb)
{
    __shared__ float esh[4*T_];
    int wslot = threadIdx.x >> 6, lane = threadIdx.x & 63;
    int gw = blockIdx.x*4 + wslot;         // B_*H_*T_ waves total
    int t = gw % T_;
    int bh = gw / T_;
    int h = bh % H_, b = bh / H_;
    int bT = b * T_;
    int colBase = h * 64;

    // q row -> registers (all lanes same row: broadcast reads)
    float qf[64];
    const int4* qp = (const int4*)(qb + (size_t)(bT + t)*D_ + colBase);
#pragma unroll
    for (int c = 0; c < 8; ++c) {
        union { int4 v; u16 s[8]; } qv; qv.v = qp[c];
#pragma unroll
        for (int i = 0; i < 8; ++i) qf[c*8+i] = b2f(qv.s[i]);
    }

    // pass 1: scores for j = lane, lane+64, lane+128
    float s3[3];
#pragma unroll
    for (int jj = 0; jj < 3; ++jj) {
        int j = jj*64 + lane;
        const int4* kp4 = (const int4*)(kb + (size_t)(bT + j)*D_ + colBase);
        float s = 0.f;
#pragma unroll
        for (int c = 0; c < 8; ++c) {
            union { int4 v; u16 s[8]; } kv; kv.v = kp4[c];
#pragma unroll
            for (int i = 0; i < 8; ++i) s += qf[c*8+i] * b2f(kv.s[i]);
        }
        s3[jj] = (j <= t) ? s * 0.125f : -1e30f;
    }
    float mloc = fmaxf(fmaxf(s3[0], s3[1]), s3[2]);
#pragma unroll
    for (int off = 32; off > 0; off >>= 1) mloc = fmaxf(mloc, __shfl_xor(mloc, off, 64));
    float l = 0.f;
#pragma unroll
    for (int jj = 0; jj < 3; ++jj) {
        float e = (s3[jj] > -1e29f) ? expf(s3[jj] - mloc) : 0.f;
        esh[wslot*T_ + jj*64 + lane] = e;
        l += e;
    }
#pragma unroll
    for (int off = 32; off > 0; off >>= 1) l += __shfl_xor(l, off, 64);
    __syncthreads();

    // pass 2: o_d = sum_j e_j v[j][d]
    int d = lane;
    const u16* vcol = vb + (size_t)bT*D_ + colBase + d;
    const float* eptr = esh + wslot*T_;
    float o = 0.f;
    for (int j = 0; j <= t; ++j)
        o += eptr[j] * b2f(vcol[(size_t)j*D_]);
    yb[(size_t)(bT + t)*D_ + colBase + d] = f2b(o / l);
}

// ---------------------------------------------------------------------------
// Final linear: out(BT x 27) = xf @ lin_w + lin_b  -> f32 output
// ---------------------------------------------------------------------------
__global__ __launch_bounds__(256) void final_kernel(const float* __restrict__ xf,
                                                    const float* __restrict__ lin_w,
                                                    const float* __restrict__ lin_b,
                                                    float* __restrict__ out)
{
    int row = blockIdx.x, tid = threadIdx.x;
    __shared__ float xs[D_];
    __shared__ float ps[27*8];
    ((float4*)xs)[tid] = ((const float4*)(xf + (size_t)row*D_))[tid];
    __syncthreads();
    if (tid < 216) {
        int c = tid >> 3, part = tid & 7;
        float acc = 0.f;
        int k0 = part*128;
        for (int k = k0; k < k0+128; ++k) acc += xs[k] * lin_w[k*27 + c];
        ps[c*8 + part] = acc;
    }
    __syncthreads();
    if (tid < 27) {
        float acc = lin_b[tid];
#pragma unroll
        for (int p = 0; p < 8; ++p) acc += ps[tid*8 + p];
        out[(size_t)row*27 + tid] = acc;
    }
}

// ---------------------------------------------------------------------------
extern "C" void kernel_launch(void* const* d_in, const int* in_sizes, int n_in,
                              void* d_out, int out_size, void* d_ws, size_t ws_size,
                              hipStream_t stream)
{
    const float* states   = (const float*)d_in[0];
    const float* actions  = (const float*)d_in[1];
    const float* rtgs     = (const float*)d_in[2];
    // d_in[3] attention_mask (all ones), d_in[4] y_len: unused
    const float* se_w1 = (const float*)d_in[5];
    const float* se_b1 = (const float*)d_in[6];
    const float* se_w2 = (const float*)d_in[7];
    const float* se_b2 = (const float*)d_in[8];
    const float* ae_w1 = (const float*)d_in[9];
    const float* ae_b1 = (const float*)d_in[10];
    const float* ae_w2 = (const float*)d_in[11];
    const float* ae_b2 = (const float*)d_in[12];
    const float* ad_bucket_w = (const float*)d_in[13];
    const float* ad_bucket_b = (const float*)d_in[14];
    const float* ad_ret_w = (const float*)d_in[15];
    const float* ad_res_w = (const float*)d_in[16];
    const float* pos_emb  = (const float*)d_in[17];
    const float* ln1_g = (const float*)d_in[18];
    const float* ln1_b = (const float*)d_in[19];
    const float* Wq = (const float*)d_in[20];
    const float* bq = (const float*)d_in[21];
    const float* Wk = (const float*)d_in[22];
    const float* bk = (const float*)d_in[23];
    const float* Wv = (const float*)d_in[24];
    const float* bv = (const float*)d_in[25];
    const float* Wp = (const float*)d_in[26];
    const float* bp = (const float*)d_in[27];
    const float* ln2_g = (const float*)d_in[28];
    const float* ln2_b = (const float*)d_in[29];
    const float* Wm1 = (const float*)d_in[30];
    const float* bm1 = (const float*)d_in[31];
    const float* Wm2 = (const float*)d_in[32];
    const float* bm2 = (const float*)d_in[33];
    const float* lin_w = (const float*)d_in[34];
    const float* lin_b = (const float*)d_in[35];

    char* w = (char*)d_ws;
    float* xf  = (float*)w;              w += (size_t)BT_*D_*4;
    u16* hb    = (u16*)w;                w += (size_t)BT_*D_*2;
    u16* qb_   = (u16*)w;                w += (size_t)BT_*D_*2;
    u16* kb_   = (u16*)w;                w += (size_t)BT_*D_*2;
    u16* vb_   = (u16*)w;                w += (size_t)BT_*D_*2;
    u16* yb_   = (u16*)w;                w += (size_t)BT_*D_*2;
    u16* midb  = (u16*)w;                w += (size_t)BT_*DF_*2;
    u16* tSb   = (u16*)w;                w += (size_t)BL_*D_*2;
    u16* tAb   = (u16*)w;                w += (size_t)BL_*D_*2;
    float* eS  = (float*)w;              w += (size_t)BL_*D_*4;
    float* eA  = (float*)w;              w += (size_t)BL_*D_*4;
    float* eR  = (float*)w;              w += (size_t)BL_*D_*4;

    // --- embeddings ---
    embed1_kernel<<<4096, 256, 0, stream>>>(states,  se_w1, se_b1, tSb, 91);
    embed1_kernel<<<4096, 256, 0, stream>>>(actions, ae_w1, ae_b1, tAb, 27);
    gemm128<1><<<dim3(8, 8),  256, 0, stream>>>(tSb, se_w2, se_b2, nullptr, eS, nullptr, BL_, D_, D_);
    gemm128<0><<<dim3(8, 8),  256, 0, stream>>>(tAb, ae_w2, ae_b2, nullptr, eA, nullptr, BL_, D_, D_);
    rtg_kernel<<<BL_, 128, 0, stream>>>(rtgs, ad_ret_w, ad_res_w, ad_bucket_w, ad_bucket_b, eR);
    assemble_kernel<<<(BT_*D_)/256, 256, 0, stream>>>(eR, eS, eA, pos_emb, xf);

    // --- transformer layers ---
    for (int i = 0; i < NL_; ++i) {
        ln_kernel<<<BT_, 256, 0, stream>>>(xf, ln1_g + i*D_, ln1_b + i*D_, hb);
        gemm128<0><<<dim3(8, 24), 256, 0, stream>>>(hb, Wq + (size_t)i*D_*D_, bq + i*D_, nullptr, nullptr, qb_, BT_, D_, D_);
        gemm128<0><<<dim3(8, 24), 256, 0, stream>>>(hb, Wk + (size_t)i*D_*D_, bk + i*D_, nullptr, nullptr, kb_, BT_, D_, D_);
        gemm128<0><<<dim3(8, 24), 256, 0, stream>>>(hb, Wv + (size_t)i*D_*D_, bv + i*D_, nullptr, nullptr, vb_, BT_, D_, D_);
        attn_kernel<<<(B_*H_*T_)/4, 256, 0, stream>>>(qb_, kb_, vb_, yb_);
        gemm128<0><<<dim3(8, 24), 256, 0, stream>>>(yb_, Wp + (size_t)i*D_*D_, bp + i*D_, xf, xf, nullptr, BT_, D_, D_);
        ln_kernel<<<BT_, 256, 0, stream>>>(xf, ln2_g + i*D_, ln2_b + i*D_, hb);
        gemm128<1><<<dim3(32, 24), 256, 0, stream>>>(hb, Wm1 + (size_t)i*D_*DF_, bm1 + i*DF_, nullptr, nullptr, midb, BT_, DF_, D_);
        gemm128<0><<<dim3(8, 24), 256, 0, stream>>>(midb, Wm2 + (size_t)i*DF_*D_, bm2 + i*D_, xf, xf, nullptr, BT_, D_, DF_);
    }

    // --- head ---
    final_kernel<<<BT_, 256, 0, stream>>>(xf, lin_w, lin_b, (float*)d_out);
}

// Round 3
// 2961.725 us; speedup vs baseline: 1.9629x; 1.9629x over previous
//
#include <hip/hip_runtime.h>
#include <cmath>

typedef unsigned short u16;
typedef unsigned int   u32;
typedef short s16x8 __attribute__((ext_vector_type(8)));
typedef float f32x4 __attribute__((ext_vector_type(4)));

#define D_  1024
#define H_  16
#define NL_ 6
#define B_  16
#define L_  64
#define T_  192
#define NB_ 100
#define DF_ 4096
#define BT_ (B_*T_)   /* 3072 rows in stream */
#define BL_ (B_*L_)   /* 1024 rows per modality */

__device__ __forceinline__ float b2f(u16 u){ u32 x = ((u32)u)<<16; return __uint_as_float(x); }
__device__ __forceinline__ u16 f2b(float f){ u32 x = __float_as_uint(f); x += 0x7fffu + ((x>>16)&1u); return (u16)(x>>16); }
__device__ __forceinline__ float gelu_f(float v){ return 0.5f*v*(1.0f+erff(v*0.70710678118f)); }

// ---------------------------------------------------------------------------
// f32 -> bf16 elementwise (weight pre-conversion), 8 elems/thread
// ---------------------------------------------------------------------------
__global__ __launch_bounds__(256) void cvt_kernel(const float* __restrict__ src,
                                                  u16* __restrict__ dst, int n8)
{
    int i = blockIdx.x*256 + threadIdx.x;
    if (i >= n8) return;
    float4 a = ((const float4*)src)[2*i];
    float4 b = ((const float4*)src)[2*i+1];
    union { int4 v; u16 s[8]; } o;
    o.s[0]=f2b(a.x); o.s[1]=f2b(a.y); o.s[2]=f2b(a.z); o.s[3]=f2b(a.w);
    o.s[4]=f2b(b.x); o.s[5]=f2b(b.y); o.s[6]=f2b(b.z); o.s[7]=f2b(b.w);
    ((int4*)dst)[i] = o.v;
}

// ---------------------------------------------------------------------------
// Small VALU GEMM for the K=91 / K=27 embedding first layers (trivial FLOPs).
// ---------------------------------------------------------------------------
__global__ __launch_bounds__(256) void embed1_kernel(const float* __restrict__ A,
                                                     const float* __restrict__ W,
                                                     const float* __restrict__ bias,
                                                     u16* __restrict__ out, int K)
{
    int idx = blockIdx.x*256 + threadIdx.x;     // 1024*1024 outputs
    int m = idx >> 10, n = idx & 1023;
    float acc = bias[n];
    for (int k = 0; k < K; ++k)
        acc += A[m*K + k] * W[k*1024 + n];
    out[idx] = f2b(gelu_f(acc));
}

// ---------------------------------------------------------------------------
// rtg embedding
// ---------------------------------------------------------------------------
__global__ __launch_bounds__(128) void rtg_kernel(const float* __restrict__ rtgs,
                                                  const float* __restrict__ ret_w,
                                                  const float* __restrict__ res_w,
                                                  const float* __restrict__ bucket_w,
                                                  const float* __restrict__ bucket_b,
                                                  float* __restrict__ eR)
{
    int r = blockIdx.x, tid = threadIdx.x;
    __shared__ float sarr[NB_];
    __shared__ float red[128];
    float rtg = rtgs[r];
    float s = 0.f;
    if (tid < NB_) {
        float v = rtg * ret_w[tid];
        s = (v > 0.f) ? v : 0.01f*v;
        sarr[tid] = s;
    }
    __syncthreads();
    float s2 = -1e30f;
    if (tid < NB_) {
        float acc = s;
        for (int m = 0; m < NB_; ++m) acc += sarr[m] * res_w[m*NB_ + tid];
        s2 = acc;
    }
    red[tid] = s2; __syncthreads();
    for (int off = 64; off > 0; off >>= 1) { if (tid < off) red[tid] = fmaxf(red[tid], red[tid+off]); __syncthreads(); }
    float mx = red[0]; __syncthreads();
    float e = (tid < NB_) ? expf(s2 - mx) : 0.f;
    red[tid] = e; __syncthreads();
    for (int off = 64; off > 0; off >>= 1) { if (tid < off) red[tid] += red[tid+off]; __syncthreads(); }
    float S = red[0]; __syncthreads();
    float bv = (100.f/99.f) * (float)tid;
    red[tid] = e * bv; __syncthreads();
    for (int off = 64; off > 0; off >>= 1) { if (tid < off) red[tid] += red[tid+off]; __syncthreads(); }
    float EB = red[0];
    float inv = 1.f/(1e-8f + S);
    float c = EB * inv, sg = S * inv;
    for (int d = tid; d < D_; d += 128)
        eR[(size_t)r*D_ + d] = c*bucket_w[d] + sg*bucket_b[d];
}

// ---------------------------------------------------------------------------
// assemble: x[b,3l+c,:] = emb_c[b,l,:] + pos[3l+c,:]   (f32 stream)
// ---------------------------------------------------------------------------
__global__ __launch_bounds__(256) void assemble_kernel(const float* __restrict__ eR,
                                                       const float* __restrict__ eS,
                                                       const float* __restrict__ eA,
                                                       const float* __restrict__ pos,
                                                       float* __restrict__ xf)
{
    int idx = blockIdx.x*256 + threadIdx.x;       // BT_*D_
    int row = idx >> 10, d = idx & 1023;
    int b = row / T_, t = row % T_;
    int l = t / 3, c = t % 3;
    const float* src = (c == 0) ? eR : (c == 1) ? eS : eA;
    xf[idx] = src[(size_t)(b*L_ + l)*D_ + d] + pos[(size_t)t*D_ + d];
}

// ---------------------------------------------------------------------------
// LayerNorm rows of f32 stream -> bf16
// ---------------------------------------------------------------------------
__global__ __launch_bounds__(256) void ln_kernel(const float* __restrict__ x,
                                                 const float* __restrict__ g,
                                                 const float* __restrict__ bb,
                                                 u16* __restrict__ out)
{
    int row = blockIdx.x, tid = threadIdx.x;
    __shared__ float rs[256], rq[256];
    float4 v = ((const float4*)(x + (size_t)row*D_))[tid];
    rs[tid] = v.x+v.y+v.z+v.w;
    rq[tid] = v.x*v.x+v.y*v.y+v.z*v.z+v.w*v.w;
    __syncthreads();
    for (int off = 128; off > 0; off >>= 1) { if (tid < off){ rs[tid]+=rs[tid+off]; rq[tid]+=rq[tid+off]; } __syncthreads(); }
    float mean = rs[0]*(1.f/(float)D_);
    float var  = rq[0]*(1.f/(float)D_) - mean*mean;
    float rstd = rsqrtf(var + 1e-5f);
    int d0 = tid*4;
    ushort4 ov;
    ov.x = f2b((v.x-mean)*rstd*g[d0+0] + bb[d0+0]);
    ov.y = f2b((v.y-mean)*rstd*g[d0+1] + bb[d0+1]);
    ov.z = f2b((v.z-mean)*rstd*g[d0+2] + bb[d0+2]);
    ov.w = f2b((v.w-mean)*rstd*g[d0+3] + bb[d0+3]);
    ((ushort4*)(out + (size_t)row*D_))[tid] = ov;
}

// ---------------------------------------------------------------------------
// MFMA bf16 GEMM: C(MxN) = act(A(MxK) @ W(KxN) + bias) [+ res].
// A bf16; W either f32 (converted in staging) or pre-converted bf16 (WBF16).
// 128x128 tile / 4 waves / BK=32, 16x16x32 bf16 MFMA.
// ---------------------------------------------------------------------------
template<int GELU_ACT, int WBF16>
__global__ __launch_bounds__(256) void gemm128(const u16* __restrict__ A,
                                               const void* __restrict__ Wp_,
                                               const float* __restrict__ bias,
                                               const float* res,
                                               float* outF,
                                               u16* outB,
                                               int M, int N, int K)
{
    __shared__ __align__(16) u16 As[128*40];
    __shared__ __align__(16) u16 Bs[128*42];
    int tid = threadIdx.x;
    int n0 = blockIdx.x * 128;
    int m0 = blockIdx.y * 128;
    int wave = tid >> 6, lane = tid & 63;
    int wm = (wave >> 1) * 64, wn = (wave & 1) * 64;
    int lr = lane & 15, lq = lane >> 4;

    f32x4 acc[4][4];
#pragma unroll
    for (int i = 0; i < 4; ++i)
#pragma unroll
        for (int j = 0; j < 4; ++j) acc[i][j] = (f32x4){0.f,0.f,0.f,0.f};

    int arow = tid >> 2, aq = tid & 3;
    int kp = tid >> 4, cc = tid & 15;

    for (int k0 = 0; k0 < K; k0 += 32) {
        *(int4*)(As + arow*40 + aq*8)      = *(const int4*)(A + (size_t)(m0+arow)*K    + k0 + aq*8);
        *(int4*)(As + (64+arow)*40 + aq*8) = *(const int4*)(A + (size_t)(m0+64+arow)*K + k0 + aq*8);
        if (WBF16) {
            const u16* wp = (const u16*)Wp_ + (size_t)(k0 + 2*kp)*N + n0 + cc*8;
            union { int4 v; u16 s[8]; } r0, r1;
            r0.v = *(const int4*)wp;
            r1.v = *(const int4*)(wp + N);
#pragma unroll
            for (int i = 0; i < 8; ++i)
                *(u32*)(Bs + (cc*8 + i)*42 + 2*kp) = (u32)r0.s[i] | ((u32)r1.s[i] << 16);
        } else {
            const float* wp = (const float*)Wp_ + (size_t)(k0 + 2*kp)*N + n0 + cc*8;
            float4 r0a = *(const float4*)(wp);
            float4 r0b = *(const float4*)(wp + 4);
            float4 r1a = *(const float4*)(wp + N);
            float4 r1b = *(const float4*)(wp + N + 4);
            float r0[8] = {r0a.x,r0a.y,r0a.z,r0a.w, r0b.x,r0b.y,r0b.z,r0b.w};
            float r1[8] = {r1a.x,r1a.y,r1a.z,r1a.w, r1b.x,r1b.y,r1b.z,r1b.w};
#pragma unroll
            for (int i = 0; i < 8; ++i)
                *(u32*)(Bs + (cc*8 + i)*42 + 2*kp) = (u32)f2b(r0[i]) | ((u32)f2b(r1[i]) << 16);
        }
        __syncthreads();

        s16x8 af[4], bf[4];
#pragma unroll
        for (int i = 0; i < 4; ++i)
            af[i] = *(const s16x8*)(As + (wm + i*16 + lr)*40 + lq*8);
#pragma unroll
        for (int j = 0; j < 4; ++j) {
            const int* bp = (const int*)(Bs + (wn + j*16 + lr)*42 + lq*8);
            union { int i4[4]; s16x8 v; } u;
            u.i4[0]=bp[0]; u.i4[1]=bp[1]; u.i4[2]=bp[2]; u.i4[3]=bp[3];
            bf[j] = u.v;
        }
#pragma unroll
        for (int i = 0; i < 4; ++i)
#pragma unroll
            for (int j = 0; j < 4; ++j)
                acc[i][j] = __builtin_amdgcn_mfma_f32_16x16x32_bf16(af[i], bf[j], acc[i][j], 0, 0, 0);
        __syncthreads();
    }

#pragma unroll
    for (int i = 0; i < 4; ++i) {
        int mbase = m0 + wm + i*16 + lq*4;
#pragma unroll
        for (int j = 0; j < 4; ++j) {
            int n = n0 + wn + j*16 + lr;
            float bvl = bias[n];
#pragma unroll
            for (int r = 0; r < 4; ++r) {
                int m = mbase + r;
                float v = acc[i][j][r] + bvl;
                if (GELU_ACT) v = gelu_f(v);
                size_t off = (size_t)m*N + n;
                if (res)  v += res[off];
                if (outF) outF[off] = v;
                if (outB) outB[off] = f2b(v);
            }
        }
    }
}

// ---------------------------------------------------------------------------
// MFMA flash-style attention. One workgroup per (b,h); 4 waves.
// K staged [t][d] stride 72 (2-way-free banks); V staged transposed [d][t]
// stride 200; S=QK^T via mfma 16x16x32; softmax in C-layout regs with 16-lane
// shuffle reductions; P goes through a per-wave LDS chunk into A-layout; PV
// via mfma; causal j-tile skipping. LDS total = 58.4 KB.
// ---------------------------------------------------------------------------
__global__ __launch_bounds__(256) void attn_mfma_kernel(const u16* __restrict__ qb,
                                                        const u16* __restrict__ kb,
                                                        const u16* __restrict__ vb,
                                                        u16* __restrict__ yb)
{
    __shared__ __align__(16) u16 Ks[192*72];
    __shared__ __align__(16) u16 Vt[64*200];
    __shared__ __align__(16) u16 Pch[4][16*40];

    int tid = threadIdx.x;
    int b = blockIdx.x >> 4, h = blockIdx.x & 15;
    int bT = b * T_;
    int colBase = h * 64;
    int w = tid >> 6, lane = tid & 63;
    int lr = lane & 15, lq = lane >> 4;

    // stage K (row-major) and V (transposed)
#pragma unroll
    for (int it = 0; it < 6; ++it) {
        int c = it*256 + tid;
        int row = c >> 3, ch = c & 7;
        *(int4*)(Ks + row*72 + ch*8) =
            *(const int4*)(kb + (size_t)(bT+row)*D_ + colBase + ch*8);
        union { int4 v; u16 s[8]; } rv;
        rv.v = *(const int4*)(vb + (size_t)(bT+row)*D_ + colBase + ch*8);
#pragma unroll
        for (int i2 = 0; i2 < 8; ++i2)
            Vt[(ch*8 + i2)*200 + row] = rv.s[i2];
    }
    __syncthreads();

    u16* Ch = Pch[w];

    for (int qi = 0; qi < 3; ++qi) {
        int qt = w + qi*4;            // q-tile index 0..11 (interleaved balance)
        int tqb = qt * 16;

        // Q A-fragments (global, L2-hot)
        const u16* qrow = qb + (size_t)(bT + tqb + lr)*D_ + colBase + lq*8;
        s16x8 af0 = *(const s16x8*)(qrow);
        s16x8 af1 = *(const s16x8*)(qrow + 32);

        // S = Q K^T  (C layout: row=lq*4+r, col=lr within j-tile)
        f32x4 sacc[12];
#pragma unroll
        for (int jt = 0; jt < 12; ++jt) {
            if (jt <= qt) {
                s16x8 bk0 = *(const s16x8*)(Ks + (jt*16 + lr)*72 + lq*8);
                s16x8 bk1 = *(const s16x8*)(Ks + (jt*16 + lr)*72 + 32 + lq*8);
                f32x4 a = (f32x4){0.f,0.f,0.f,0.f};
                a = __builtin_amdgcn_mfma_f32_16x16x32_bf16(af0, bk0, a, 0, 0, 0);
                a = __builtin_amdgcn_mfma_f32_16x16x32_bf16(af1, bk1, a, 0, 0, 0);
                sacc[jt] = a;
            }
        }

        // mask + row max
        float mrow[4] = {-1e30f,-1e30f,-1e30f,-1e30f};
#pragma unroll
        for (int jt = 0; jt < 12; ++jt) if (jt <= qt) {
#pragma unroll
            for (int r = 0; r < 4; ++r) {
                bool valid = (jt < qt) || (lr <= lq*4 + r);
                float s = valid ? sacc[jt][r]*0.125f : -1e30f;
                sacc[jt][r] = s;
                mrow[r] = fmaxf(mrow[r], s);
            }
        }
#pragma unroll
        for (int r = 0; r < 4; ++r) {
#pragma unroll
            for (int off = 1; off < 16; off <<= 1)
                mrow[r] = fmaxf(mrow[r], __shfl_xor(mrow[r], off, 64));
        }

        // exp + row sum (e kept in sacc registers)
        float lrow[4] = {0.f,0.f,0.f,0.f};
#pragma unroll
        for (int jt = 0; jt < 12; ++jt) if (jt <= qt) {
#pragma unroll
            for (int r = 0; r < 4; ++r) {
                float e = __expf(sacc[jt][r] - mrow[r]);
                sacc[jt][r] = e;
                lrow[r] += e;
            }
        }
#pragma unroll
        for (int r = 0; r < 4; ++r) {
#pragma unroll
            for (int off = 1; off < 16; off <<= 1)
                lrow[r] += __shfl_xor(lrow[r], off, 64);
            lrow[r] = 1.f / lrow[r];
        }

        // PV: per 32-key chunk, write P chunk (C->A layout via LDS), mfma
        int nkt = (qt + 2) >> 1;
        f32x4 oacc[4];
#pragma unroll
        for (int nt = 0; nt < 4; ++nt) oacc[nt] = (f32x4){0.f,0.f,0.f,0.f};

#pragma unroll
        for (int kt = 0; kt < 6; ++kt) if (kt < nkt) {
            int jt0 = 2*kt, jt1 = 2*kt + 1;
#pragma unroll
            for (int r = 0; r < 4; ++r) {
                u16 e0 = f2b(sacc[jt0][r]);
                u16 e1 = (jt1 <= qt) ? f2b(sacc[jt1][r]) : (u16)0;
                Ch[(lq*4 + r)*40 + lr]      = e0;
                Ch[(lq*4 + r)*40 + 16 + lr] = e1;
            }
            s16x8 ap = *(const s16x8*)(Ch + lr*40 + lq*8);
#pragma unroll
            for (int nt = 0; nt < 4; ++nt) {
                s16x8 bv = *(const s16x8*)(Vt + (nt*16 + lr)*200 + kt*32 + lq*8);
                oacc[nt] = __builtin_amdgcn_mfma_f32_16x16x32_bf16(ap, bv, oacc[nt], 0, 0, 0);
            }
        }

        // store O (C layout), normalized by 1/l
#pragma unroll
        for (int nt = 0; nt < 4; ++nt)
#pragma unroll
            for (int r = 0; r < 4; ++r)
                yb[(size_t)(bT + tqb + lq*4 + r)*D_ + colBase + nt*16 + lr] =
                    f2b(oacc[nt][r] * lrow[r]);
    }
}

// ---------------------------------------------------------------------------
// Final linear: out(BT x 27) = xf @ lin_w + lin_b  -> f32 output
// ---------------------------------------------------------------------------
__global__ __launch_bounds__(256) void final_kernel(const float* __restrict__ xf,
                                                    const float* __restrict__ lin_w,
                                                    const float* __restrict__ lin_b,
                                                    float* __restrict__ out)
{
    int row = blockIdx.x, tid = threadIdx.x;
    __shared__ float xs[D_];
    __shared__ float ps[27*8];
    ((float4*)xs)[tid] = ((const float4*)(xf + (size_t)row*D_))[tid];
    __syncthreads();
    if (tid < 216) {
        int c = tid >> 3, part = tid & 7;
        float acc = 0.f;
        int k0 = part*128;
        for (int k = k0; k < k0+128; ++k) acc += xs[k] * lin_w[k*27 + c];
        ps[c*8 + part] = acc;
    }
    __syncthreads();
    if (tid < 27) {
        float acc = lin_b[tid];
#pragma unroll
        for (int p = 0; p < 8; ++p) acc += ps[tid*8 + p];
        out[(size_t)row*27 + tid] = acc;
    }
}

// ---------------------------------------------------------------------------
extern "C" void kernel_launch(void* const* d_in, const int* in_sizes, int n_in,
                              void* d_out, int out_size, void* d_ws, size_t ws_size,
                              hipStream_t stream)
{
    const float* states   = (const float*)d_in[0];
    const float* actions  = (const float*)d_in[1];
    const float* rtgs     = (const float*)d_in[2];
    const float* se_w1 = (const float*)d_in[5];
    const float* se_b1 = (const float*)d_in[6];
    const float* se_w2 = (const float*)d_in[7];
    const float* se_b2 = (const float*)d_in[8];
    const float* ae_w1 = (const float*)d_in[9];
    const float* ae_b1 = (const float*)d_in[10];
    const float* ae_w2 = (const float*)d_in[11];
    const float* ae_b2 = (const float*)d_in[12];
    const float* ad_bucket_w = (const float*)d_in[13];
    const float* ad_bucket_b = (const float*)d_in[14];
    const float* ad_ret_w = (const float*)d_in[15];
    const float* ad_res_w = (const float*)d_in[16];
    const float* pos_emb  = (const float*)d_in[17];
    const float* ln1_g = (const float*)d_in[18];
    const float* ln1_b = (const float*)d_in[19];
    const float* Wq = (const float*)d_in[20];
    const float* bq = (const float*)d_in[21];
    const float* Wk = (const float*)d_in[22];
    const float* bk = (const float*)d_in[23];
    const float* Wv = (const float*)d_in[24];
    const float* bv = (const float*)d_in[25];
    const float* Wp = (const float*)d_in[26];
    const float* bp = (const float*)d_in[27];
    const float* ln2_g = (const float*)d_in[28];
    const float* ln2_b = (const float*)d_in[29];
    const float* Wm1 = (const float*)d_in[30];
    const float* bm1 = (const float*)d_in[31];
    const float* Wm2 = (const float*)d_in[32];
    const float* bm2 = (const float*)d_in[33];
    const float* lin_w = (const float*)d_in[34];
    const float* lin_b = (const float*)d_in[35];

    char* w = (char*)d_ws;
    auto take = [&](size_t bytes) { char* p = w; w += (bytes + 255) & ~(size_t)255; return p; };

    float* xf  = (float*)take((size_t)BT_*D_*4);
    u16* hb    = (u16*)take((size_t)BT_*D_*2);
    u16* qb_   = (u16*)take((size_t)BT_*D_*2);
    u16* kb_   = (u16*)take((size_t)BT_*D_*2);
    u16* vb_   = (u16*)take((size_t)BT_*D_*2);
    u16* yb_   = (u16*)take((size_t)BT_*D_*2);
    u16* midb  = (u16*)take((size_t)BT_*DF_*2);
    u16* tSb   = (u16*)take((size_t)BL_*D_*2);
    u16* tAb   = (u16*)take((size_t)BL_*D_*2);
    float* eS  = (float*)take((size_t)BL_*D_*4);
    float* eA  = (float*)take((size_t)BL_*D_*4);
    float* eR  = (float*)take((size_t)BL_*D_*4);

    // optional bf16 weight area
    u16* Wqb  = (u16*)take((size_t)NL_*D_*D_*2);
    u16* Wkb  = (u16*)take((size_t)NL_*D_*D_*2);
    u16* Wvb  = (u16*)take((size_t)NL_*D_*D_*2);
    u16* Wpb  = (u16*)take((size_t)NL_*D_*D_*2);
    u16* Wm1b = (u16*)take((size_t)NL_*D_*DF_*2);
    u16* Wm2b = (u16*)take((size_t)NL_*DF_*D_*2);
    u16* sw2b = (u16*)take((size_t)D_*D_*2);
    u16* aw2b = (u16*)take((size_t)D_*D_*2);
    size_t fullUsed = (size_t)(w - (char*)d_ws);
    bool useBf16W = (ws_size >= fullUsed);

    if (useBf16W) {
        int nQ  = NL_*D_*D_/8;   // 786432
        int nM  = NL_*D_*DF_/8;  // 3145728
        int nE  = D_*D_/8;       // 131072
        cvt_kernel<<<(nQ+255)/256, 256, 0, stream>>>(Wq,  Wqb,  nQ);
        cvt_kernel<<<(nQ+255)/256, 256, 0, stream>>>(Wk,  Wkb,  nQ);
        cvt_kernel<<<(nQ+255)/256, 256, 0, stream>>>(Wv,  Wvb,  nQ);
        cvt_kernel<<<(nQ+255)/256, 256, 0, stream>>>(Wp,  Wpb,  nQ);
        cvt_kernel<<<(nM+255)/256, 256, 0, stream>>>(Wm1, Wm1b, nM);
        cvt_kernel<<<(nM+255)/256, 256, 0, stream>>>(Wm2, Wm2b, nM);
        cvt_kernel<<<(nE+255)/256, 256, 0, stream>>>(se_w2, sw2b, nE);
        cvt_kernel<<<(nE+255)/256, 256, 0, stream>>>(ae_w2, aw2b, nE);
    }

    // --- embeddings ---
    embed1_kernel<<<4096, 256, 0, stream>>>(states,  se_w1, se_b1, tSb, 91);
    embed1_kernel<<<4096, 256, 0, stream>>>(actions, ae_w1, ae_b1, tAb, 27);
    if (useBf16W) {
        gemm128<1,1><<<dim3(8, 8),  256, 0, stream>>>(tSb, sw2b, se_b2, nullptr, eS, nullptr, BL_, D_, D_);
        gemm128<0,1><<<dim3(8, 8),  256, 0, stream>>>(tAb, aw2b, ae_b2, nullptr, eA, nullptr, BL_, D_, D_);
    } else {
        gemm128<1,0><<<dim3(8, 8),  256, 0, stream>>>(tSb, se_w2, se_b2, nullptr, eS, nullptr, BL_, D_, D_);
        gemm128<0,0><<<dim3(8, 8),  256, 0, stream>>>(tAb, ae_w2, ae_b2, nullptr, eA, nullptr, BL_, D_, D_);
    }
    rtg_kernel<<<BL_, 128, 0, stream>>>(rtgs, ad_ret_w, ad_res_w, ad_bucket_w, ad_bucket_b, eR);
    assemble_kernel<<<(BT_*D_)/256, 256, 0, stream>>>(eR, eS, eA, pos_emb, xf);

    // --- transformer layers ---
    for (int i = 0; i < NL_; ++i) {
        ln_kernel<<<BT_, 256, 0, stream>>>(xf, ln1_g + i*D_, ln1_b + i*D_, hb);
        if (useBf16W) {
            gemm128<0,1><<<dim3(8, 24), 256, 0, stream>>>(hb, Wqb + (size_t)i*D_*D_, bq + i*D_, nullptr, nullptr, qb_, BT_, D_, D_);
            gemm128<0,1><<<dim3(8, 24), 256, 0, stream>>>(hb, Wkb + (size_t)i*D_*D_, bk + i*D_, nullptr, nullptr, kb_, BT_, D_, D_);
            gemm128<0,1><<<dim3(8, 24), 256, 0, stream>>>(hb, Wvb + (size_t)i*D_*D_, bv + i*D_, nullptr, nullptr, vb_, BT_, D_, D_);
        } else {
            gemm128<0,0><<<dim3(8, 24), 256, 0, stream>>>(hb, Wq + (size_t)i*D_*D_, bq + i*D_, nullptr, nullptr, qb_, BT_, D_, D_);
            gemm128<0,0><<<dim3(8, 24), 256, 0, stream>>>(hb, Wk + (size_t)i*D_*D_, bk + i*D_, nullptr, nullptr, kb_, BT_, D_, D_);
            gemm128<0,0><<<dim3(8, 24), 256, 0, stream>>>(hb, Wv + (size_t)i*D_*D_, bv + i*D_, nullptr, nullptr, vb_, BT_, D_, D_);
        }
        attn_mfma_kernel<<<B_*H_, 256, 0, stream>>>(qb_, kb_, vb_, yb_);
        if (useBf16W) {
            gemm128<0,1><<<dim3(8, 24), 256, 0, stream>>>(yb_, Wpb + (size_t)i*D_*D_, bp + i*D_, xf, xf, nullptr, BT_, D_, D_);
        } else {
            gemm128<0,0><<<dim3(8, 24), 256, 0, stream>>>(yb_, Wp + (size_t)i*D_*D_, bp + i*D_, xf, xf, nullptr, BT_, D_, D_);
        }
        ln_kernel<<<BT_, 256, 0, stream>>>(xf, ln2_g + i*D_, ln2_b + i*D_, hb);
        if (useBf16W) {
            gemm128<1,1><<<dim3(32, 24), 256, 0, stream>>>(hb, Wm1b + (size_t)i*D_*DF_, bm1 + i*DF_, nullptr, nullptr, midb, BT_, DF_, D_);
            gemm128<0,1><<<dim3(8, 24), 256, 0, stream>>>(midb, Wm2b + (size_t)i*DF_*D_, bm2 + i*D_, xf, xf, nullptr, BT_, D_, DF_);
        } else {
            gemm128<1,0><<<dim3(32, 24), 256, 0, stream>>>(hb, Wm1 + (size_t)i*D_*DF_, bm1 + i*DF_, nullptr, nullptr, midb, BT_, DF_, D_);
            gemm128<0,0><<<dim3(8, 24), 256, 0, stream>>>(midb, Wm2 + (size_t)i*DF_*D_, bm2 + i*D_, xf, xf, nullptr, BT_, D_, DF_);
        }
    }

    // --- head ---
    final_kernel<<<BT_, 256, 0, stream>>>(xf, lin_w, lin_b, (float*)d_out);
}